// Round 9
// baseline (214.991 us; speedup 1.0000x reference)
//
#include <hip/hip_runtime.h>
#include <math.h>

typedef _Float16 f16;
typedef _Float16 f16x4 __attribute__((ext_vector_type(4)));
typedef _Float16 f16x8 __attribute__((ext_vector_type(8)));
typedef __bf16 bf16x2 __attribute__((ext_vector_type(2)));
typedef __bf16 bf16x4 __attribute__((ext_vector_type(4)));
typedef __bf16 bf16x4a4 __attribute__((ext_vector_type(4), aligned(4)));
typedef short s16x4 __attribute__((ext_vector_type(4)));
typedef short s16x4a4 __attribute__((ext_vector_type(4), aligned(4)));
typedef float f32x4 __attribute__((ext_vector_type(4)));

#define MFMA_F16(a, b, c)  __builtin_amdgcn_mfma_f32_16x16x32_f16(a, b, c, 0, 0, 0)
#define MFMA_BF16_K16(a, b, c) __builtin_amdgcn_mfma_f32_16x16x16bf16_1k(a, b, c, 0, 0, 0)

static __device__ inline f16x8 cvt8(const float* p) {
    const float4* p4 = (const float4*)p;
    float4 u0 = p4[0], u1 = p4[1];
    f16x8 r;
    r[0] = (f16)u0.x; r[1] = (f16)u0.y; r[2] = (f16)u0.z; r[3] = (f16)u0.w;
    r[4] = (f16)u1.x; r[5] = (f16)u1.y; r[6] = (f16)u1.z; r[7] = (f16)u1.w;
    return r;
}

// ---------------------------------------------------------------------------
// Fused producer (unchanged from R7). Blocks 0..1215: (b,g,hp) rows ->
// Q,K,V via f16 MFMA; block 1216 builds relp.
// Layouts: Qb f16 [pos][g*128 + oc]; Kb f16 [b][g][hp][wp][c];
//          VtA bf16 [b][g][c][hp][idx=wp (40)]; VtB same but idx = wp-1.
// ---------------------------------------------------------------------------
__global__ __launch_bounds__(256) void produce_kernel(
    const float* __restrict__ x,
    const float* __restrict__ wq, const float* __restrict__ bq,
    const float* __restrict__ wk, const float* __restrict__ bk,
    const float* __restrict__ wv, const float* __restrict__ bv,
    const float* __restrict__ rel_h, const float* __restrict__ rel_w,
    f16* __restrict__ Qb, f16* __restrict__ Kb,
    __bf16* __restrict__ VtA, __bf16* __restrict__ VtB,
    f16* __restrict__ relp) {
    int bid = blockIdx.x;
    int t = threadIdx.x;

    if (bid == 1216) {  // rel' table: key=(gp*7+kh)*8+kw, channel c
        for (int idx = t; idx < 448 * 32; idx += 256) {
            int c = idx & 31, key = idx >> 5;
            int kw = key & 7, ghk = key >> 3;
            int gp = (ghk * 37) >> 8;
            int kh = ghk - gp * 7;
            float v = 0.f;
            if (kw < 7)
                v = (c < 16) ? rel_h[c * 56 + gp * 7 + kh]
                             : rel_w[(c - 16) * 56 + gp * 7 + kw];
            relp[idx] = (f16)v;
        }
        return;
    }

    int hp = bid % 38, g = (bid / 38) & 7, b = bid / 304;
    bool hin = (hp >= 3 && hp < 35);
    size_t kvbase = (size_t)(b * 8 + g);

    if (!hin) {  // pure-bias row (h padding)
        for (int idx = t; idx < 38 * 32; idx += 256) {
            int wp = idx >> 5, c = idx & 31;
            Kb[((kvbase * 38 + hp) * 38 + wp) * 32 + c] = (f16)bk[g * 32 + c];
        }
        for (int idx = t; idx < 40 * 32; idx += 256) {
            int i = idx >> 5, c = idx & 31;
            size_t vo = ((kvbase * 32 + c) * 38 + hp) * 40;
            __bf16 bb = (__bf16)bv[g * 32 + c];
            VtA[vo + i] = (i < 38) ? bb : (__bf16)0.f;
            VtB[vo + i] = (i < 37) ? bb : (__bf16)0.f;  // idx i = wp i+1
        }
        return;
    }

    int h = hp - 3;
    __shared__ __align__(16) f16 xTl[32 * 40];  // [w][ic], stride 40

    {   // stage x^T (each thread one float4 along w)
        int ic = t >> 3, w = (t & 7) * 4;
        float4 xv = *(const float4*)(x + (((size_t)b * 256 + g * 32 + ic) * 32 + h) * 32 + w);
        xTl[(w + 0) * 40 + ic] = (f16)xv.x;
        xTl[(w + 1) * 40 + ic] = (f16)xv.y;
        xTl[(w + 2) * 40 + ic] = (f16)xv.z;
        xTl[(w + 3) * 40 + ic] = (f16)xv.w;
    }
    __syncthreads();

    int l15 = t & 15, quad = (t >> 4) & 3, wave = t >> 6;

    f16x8 xf0 = *(const f16x8*)(xTl + l15 * 40 + quad * 8);
    f16x8 xf1 = *(const f16x8*)(xTl + (16 + l15) * 40 + quad * 8);

    // ---- Q: A=wq rows=oc; wave covers oc-tiles wave*2 + {0,1} ----
#pragma unroll
    for (int i = 0; i < 2; ++i) {
        int mq = wave * 2 + i;  // oc-tile 0..7
        f16x8 wf = cvt8(wq + ((size_t)g * 128 + mq * 16 + l15) * 32 + quad * 8);
        float4 b4 = *(const float4*)(bq + g * 128 + mq * 16 + quad * 4);
#pragma unroll
        for (int Nt = 0; Nt < 2; ++Nt) {
            f32x4 d = {0.f, 0.f, 0.f, 0.f};
            d = MFMA_F16(wf, Nt ? xf1 : xf0, d);
            f16x4 q4;
            q4[0] = (f16)(d[0] + b4.x); q4[1] = (f16)(d[1] + b4.y);
            q4[2] = (f16)(d[2] + b4.z); q4[3] = (f16)(d[3] + b4.w);
            int w = Nt * 16 + l15;
            *(f16x4*)(Qb + (size_t)((b * 32 + h) * 32 + w) * 1024 + g * 128 + mq * 16 + quad * 4) = q4;
        }
    }

    if (wave < 2) {
        // ---- K: A=wk rows=c; wave = c-tile ----
        f16x8 wf = cvt8(wk + ((size_t)g * 32 + wave * 16 + l15) * 32 + quad * 8);
        float4 b4 = *(const float4*)(bk + g * 32 + wave * 16 + quad * 4);
#pragma unroll
        for (int Nt = 0; Nt < 2; ++Nt) {
            f32x4 d = {0.f, 0.f, 0.f, 0.f};
            d = MFMA_F16(wf, Nt ? xf1 : xf0, d);
            f16x4 k4;
            k4[0] = (f16)(d[0] + b4.x); k4[1] = (f16)(d[1] + b4.y);
            k4[2] = (f16)(d[2] + b4.z); k4[3] = (f16)(d[3] + b4.w);
            int wp = Nt * 16 + l15 + 3;
            *(f16x4*)(Kb + ((kvbase * 38 + hp) * 38 + wp) * 32 + wave * 16 + quad * 4) = k4;
        }
    } else {
        // ---- V: A=x^T rows=wp; wave-2 = c-tile ----
        int Nt = wave - 2;
        f16x8 wf = cvt8(wv + ((size_t)g * 32 + Nt * 16 + l15) * 32 + quad * 8);
        float bias = bv[g * 32 + Nt * 16 + l15];
        int c = Nt * 16 + l15;
        size_t vo = ((kvbase * 32 + c) * 38 + hp) * 40;
#pragma unroll
        for (int Mt = 0; Mt < 2; ++Mt) {
            f32x4 d = {0.f, 0.f, 0.f, 0.f};
            d = MFMA_F16(Mt ? xf1 : xf0, wf, d);
            __bf16 v0 = (__bf16)(d[0] + bias), v1 = (__bf16)(d[1] + bias);
            __bf16 v2 = (__bf16)(d[2] + bias), v3 = (__bf16)(d[3] + bias);
            int wp0 = Mt * 16 + quad * 4 + 3;  // odd start
            VtA[vo + wp0] = v0;
            bf16x2 mid; mid[0] = v1; mid[1] = v2;
            *(bf16x2*)(VtA + vo + wp0 + 1) = mid;   // idx even -> 4B aligned
            VtA[vo + wp0 + 3] = v3;
            bf16x4a4 p4; p4[0] = v0; p4[1] = v1; p4[2] = v2; p4[3] = v3;
            *(bf16x4a4*)(VtB + vo + wp0 - 1) = p4;  // idx even -> 4B aligned
        }
    }

    // ---- wp borders (bias) + zero pads ----
    for (int idx = t; idx < 192; idx += 256) {
        int wi = idx >> 5, c = idx & 31;
        int wp = (wi < 3) ? wi : (32 + wi);  // {0,1,2,35,36,37}
        Kb[((kvbase * 38 + hp) * 38 + wp) * 32 + c] = (f16)bk[g * 32 + c];
        size_t vo = ((kvbase * 32 + c) * 38 + hp) * 40;
        __bf16 bb = (__bf16)bv[g * 32 + c];
        VtA[vo + wp] = bb;
        if (wp >= 1) VtB[vo + wp - 1] = bb;
    }
    for (int idx = t; idx < 160; idx += 256) {  // VtA idx 38,39; VtB idx 37,38,39
        int c = idx / 5, j = idx % 5;
        size_t vo = ((kvbase * 32 + c) * 38 + hp) * 40;
        if (j < 2) VtA[vo + 38 + j] = (__bf16)0.f;
        else       VtB[vo + 35 + j] = (__bf16)0.f;
    }
}

// ---------------------------------------------------------------------------
// MFMA attention, split-K: 2 waves per position (wave w handles gp 4w..4w+3),
// zero-LDS main loop (P register-resident via transposed scores), cross-wave
// combine of partial O^T + fsum through 5 KB LDS, one barrier.
// Grid 4096 blocks x 128 thr = 8192 waves = 32 waves/CU (full capacity).
// ---------------------------------------------------------------------------
__global__ __launch_bounds__(128, 8) void attn_kernel(
    const f16* __restrict__ Qb, const f16* __restrict__ Kb,
    const __bf16* __restrict__ VtA, const __bf16* __restrict__ VtB,
    const f16* __restrict__ relp, float* __restrict__ out) {
    int bid = blockIdx.x;
    int t = threadIdx.x;
    int wvi = t >> 6;
    int pid = (bid & 7) * 512 + (bid >> 3);  // XCD swizzle, one position/block
    int y = pid & 31, x = (pid >> 5) & 31, b = pid >> 10;

    __shared__ __align__(16) float accS[64 * 20];  // wave1 partials, stride 20

    int lane = t & 63;
    int l15 = lane & 15, quad = lane >> 4, kwl = lane & 7, p8 = (lane >> 3) & 1;
    bool oddq = (quad & 1);
    int kw0 = (quad & 1) * 4;
    int gph = quad >> 1;

    // Q fragments (B-role: n=qi=l15, k=c=quad*8+j)
    f16x8 qf[2];
    {
        const f16* qp = Qb + (size_t)pid * 1024;
        qf[0] = *(const f16x8*)(qp + l15 * 32 + quad * 8);
        qf[1] = *(const f16x8*)(qp + (16 + l15) * 32 + quad * 8);
    }

    float fsumT[2] = {0.f, 0.f};
    f32x4 acc[2][2];  // [ct][Mt]: O^T rows c=ct*16+quad*4+r, cols qi tile Mt
#pragma unroll
    for (int ct = 0; ct < 2; ++ct)
#pragma unroll
        for (int m = 0; m < 2; ++m) acc[ct][m] = (f32x4){0.f, 0.f, 0.f, 0.f};

    int yk = y + kwl;
    if (yk > 37) yk = 37;  // masked row: clamp (finite garbage, exp->0)
    const __bf16* __restrict__ Vsel = (y & 1) ? VtB : VtA;
    int yv = (y & ~1) + kw0;

    for (int chunk = wvi * 2; chunk < wvi * 2 + 2; ++chunk) {
        int gpr = chunk * 2 + p8;   // this lane's key-row group (K/relp)
        int gpv = chunk * 2 + gph;  // this lane's V-fragment group
        const f16* kbp = Kb + ((((size_t)(b * 8 + gpr) * 38 + x) * 38 + yk) << 5) + quad * 8;
        const f16* rpp = relp + ((size_t)(gpr * 56 + kwl) << 5) + quad * 8;
        const __bf16* vp0 = Vsel + (((size_t)(b * 8 + gpv) * 32 + l15) * 38 + x) * 40 + yv;
        const __bf16* vp1 = vp0 + (size_t)16 * 38 * 40;
#pragma unroll
        for (int kh = 0; kh < 7; ++kh) {
            f16x8 kb = *(const f16x8*)kbp;  kbp += 38 * 32;
            f16x8 rp = *(const f16x8*)rpp;  rpp += 256;
            kb += rp;  // K' = K + rel'
            s16x4a4 vf0 = *(const s16x4a4*)vp0;  vp0 += 40;
            s16x4a4 vf1 = *(const s16x4a4*)vp1;  vp1 += 40;
#pragma unroll
            for (int Mt = 0; Mt < 2; ++Mt) {
                f32x4 d = {0.f, 0.f, 0.f, 0.f};
                d = MFMA_F16(kb, qf[Mt], d);  // S^T: rows=keys, cols=qi
                float e0 = __expf(d[0]);
                float e1 = __expf(d[1]);
                float e2 = __expf(d[2]);
                float e3 = oddq ? 0.f : __expf(d[3]);  // kw=7 mask
                fsumT[Mt] += (e0 + e1) + (e2 + e3);
                bf16x4 pb;
                pb[0] = (__bf16)e0; pb[1] = (__bf16)e1;
                pb[2] = (__bf16)e2; pb[3] = (__bf16)e3;
                s16x4 pbi = __builtin_bit_cast(s16x4, pb);
                acc[0][Mt] = MFMA_BF16_K16((s16x4)vf0, pbi, acc[0][Mt]);
                acc[1][Mt] = MFMA_BF16_K16((s16x4)vf1, pbi, acc[1][Mt]);
            }
        }
    }

    // ---- intra-wave fsum reduce across quads ----
#pragma unroll
    for (int m = 0; m < 2; ++m) {
        fsumT[m] += __shfl_xor(fsumT[m], 16);
        fsumT[m] += __shfl_xor(fsumT[m], 32);
    }

    // ---- cross-wave combine ----
    if (wvi == 1) {
        float* s = accS + lane * 20;
        *(f32x4*)(s + 0)  = acc[0][0];
        *(f32x4*)(s + 4)  = acc[0][1];
        *(f32x4*)(s + 8)  = acc[1][0];
        *(f32x4*)(s + 12) = acc[1][1];
        s[16] = fsumT[0];
        s[17] = fsumT[1];
    }
    __syncthreads();
    if (wvi == 1) return;

    {
        const float* s = accS + lane * 20;
        acc[0][0] += *(const f32x4*)(s + 0);
        acc[0][1] += *(const f32x4*)(s + 4);
        acc[1][0] += *(const f32x4*)(s + 8);
        acc[1][1] += *(const f32x4*)(s + 12);
        fsumT[0] += s[16];
        fsumT[1] += s[17];
    }
    float inv[2] = {1.0f / fsumT[0], 1.0f / fsumT[1]};

    // ---- epilogue: normalize (lane-uniform inv), head-sum over l15&3 ----
#pragma unroll
    for (int Mt = 0; Mt < 2; ++Mt)
#pragma unroll
        for (int ct = 0; ct < 2; ++ct) {
            float v[4];
#pragma unroll
            for (int r = 0; r < 4; ++r) {
                v[r] = acc[ct][Mt][r] * inv[Mt];
                v[r] += __shfl_xor(v[r], 1);
                v[r] += __shfl_xor(v[r], 2);
            }
            if ((l15 & 3) == 0) {
                int g = Mt * 4 + (l15 >> 2);
                float4 o4 = {v[0], v[1], v[2], v[3]};
                *(float4*)(out + ((((size_t)(b * 8 + g) * 32 + x) * 32 + y) << 5) +
                           ct * 16 + quad * 4) = o4;
            }
        }
}

// ---------------------------------------------------------------------------
extern "C" void kernel_launch(void* const* d_in, const int* in_sizes, int n_in,
                              void* d_out, int out_size, void* d_ws, size_t ws_size,
                              hipStream_t stream) {
    const float* x     = (const float*)d_in[0];
    const float* wq    = (const float*)d_in[1];
    const float* bq    = (const float*)d_in[2];
    const float* wk    = (const float*)d_in[3];
    const float* bk    = (const float*)d_in[4];
    const float* wv    = (const float*)d_in[5];
    const float* bv    = (const float*)d_in[6];
    const float* rel_h = (const float*)d_in[7];
    const float* rel_w = (const float*)d_in[8];
    float* out = (float*)d_out;

    // ws layout (bytes):
    //   Qb  f16 : 4096*1024*2        = 8,388,608
    //   Kb  f16 : 4*8*38*38*32*2     = 2,957,312
    //   VtA bf16: 4*8*32*38*40*2     = 3,112,960
    //   VtB bf16: 3,112,960
    //   relp f16: 448*32*2           = 28,672
    unsigned char* ws = (unsigned char*)d_ws;
    f16*    Qb   = (f16*)ws;
    f16*    Kb   = (f16*)(ws + 8388608);
    __bf16* VtA  = (__bf16*)(ws + 8388608 + 2957312);
    __bf16* VtB  = (__bf16*)(ws + 8388608 + 2957312 + 3112960);
    f16*    relp = (f16*)(ws + 8388608 + 2957312 + 3112960 + 3112960);

    hipLaunchKernelGGL(produce_kernel, dim3(1217), dim3(256), 0, stream,
                       x, wq, bq, wk, bk, wv, bv, rel_h, rel_w, Qb, Kb, VtA, VtB, relp);
    hipLaunchKernelGGL(attn_kernel, dim3(4096), dim3(128), 0, stream,
                       Qb, Kb, VtA, VtB, relp, out);
}

// Round 10
// 129.311 us; speedup vs baseline: 1.6626x; 1.6626x over previous
//
#include <hip/hip_runtime.h>
#include <math.h>

typedef _Float16 f16;
typedef _Float16 f16x4 __attribute__((ext_vector_type(4)));
typedef _Float16 f16x8 __attribute__((ext_vector_type(8)));
typedef __bf16 bf16x2 __attribute__((ext_vector_type(2)));
typedef __bf16 bf16x4 __attribute__((ext_vector_type(4)));
typedef __bf16 bf16x4a4 __attribute__((ext_vector_type(4), aligned(4)));
typedef short s16x4 __attribute__((ext_vector_type(4)));
typedef short s16x4a4 __attribute__((ext_vector_type(4), aligned(4)));
typedef float f32x4 __attribute__((ext_vector_type(4)));

#define MFMA_F16(a, b, c)  __builtin_amdgcn_mfma_f32_16x16x32_f16(a, b, c, 0, 0, 0)
#define MFMA_BF16_K16(a, b, c) __builtin_amdgcn_mfma_f32_16x16x16bf16_1k(a, b, c, 0, 0, 0)

static __device__ inline f16x8 cvt8(const float* p) {
    const float4* p4 = (const float4*)p;
    float4 u0 = p4[0], u1 = p4[1];
    f16x8 r;
    r[0] = (f16)u0.x; r[1] = (f16)u0.y; r[2] = (f16)u0.z; r[3] = (f16)u0.w;
    r[4] = (f16)u1.x; r[5] = (f16)u1.y; r[6] = (f16)u1.z; r[7] = (f16)u1.w;
    return r;
}

// ---------------------------------------------------------------------------
// Fused producer (unchanged from R7). Blocks 0..1215: (b,g,hp) rows ->
// Q,K,V via f16 MFMA; block 1216 builds relp.
// Layouts: Qb f16 [pos][g*128 + oc]; Kb f16 [b][g][hp][wp][c];
//          VtA bf16 [b][g][c][hp][idx=wp (40)]; VtB same but idx = wp-1.
// ---------------------------------------------------------------------------
__global__ __launch_bounds__(256) void produce_kernel(
    const float* __restrict__ x,
    const float* __restrict__ wq, const float* __restrict__ bq,
    const float* __restrict__ wk, const float* __restrict__ bk,
    const float* __restrict__ wv, const float* __restrict__ bv,
    const float* __restrict__ rel_h, const float* __restrict__ rel_w,
    f16* __restrict__ Qb, f16* __restrict__ Kb,
    __bf16* __restrict__ VtA, __bf16* __restrict__ VtB,
    f16* __restrict__ relp) {
    int bid = blockIdx.x;
    int t = threadIdx.x;

    if (bid == 1216) {  // rel' table: key=(gp*7+kh)*8+kw, channel c
        for (int idx = t; idx < 448 * 32; idx += 256) {
            int c = idx & 31, key = idx >> 5;
            int kw = key & 7, ghk = key >> 3;
            int gp = (ghk * 37) >> 8;
            int kh = ghk - gp * 7;
            float v = 0.f;
            if (kw < 7)
                v = (c < 16) ? rel_h[c * 56 + gp * 7 + kh]
                             : rel_w[(c - 16) * 56 + gp * 7 + kw];
            relp[idx] = (f16)v;
        }
        return;
    }

    int hp = bid % 38, g = (bid / 38) & 7, b = bid / 304;
    bool hin = (hp >= 3 && hp < 35);
    size_t kvbase = (size_t)(b * 8 + g);

    if (!hin) {  // pure-bias row (h padding)
        for (int idx = t; idx < 38 * 32; idx += 256) {
            int wp = idx >> 5, c = idx & 31;
            Kb[((kvbase * 38 + hp) * 38 + wp) * 32 + c] = (f16)bk[g * 32 + c];
        }
        for (int idx = t; idx < 40 * 32; idx += 256) {
            int i = idx >> 5, c = idx & 31;
            size_t vo = ((kvbase * 32 + c) * 38 + hp) * 40;
            __bf16 bb = (__bf16)bv[g * 32 + c];
            VtA[vo + i] = (i < 38) ? bb : (__bf16)0.f;
            VtB[vo + i] = (i < 37) ? bb : (__bf16)0.f;  // idx i = wp i+1
        }
        return;
    }

    int h = hp - 3;
    __shared__ __align__(16) f16 xTl[32 * 40];  // [w][ic], stride 40

    {   // stage x^T (each thread one float4 along w)
        int ic = t >> 3, w = (t & 7) * 4;
        float4 xv = *(const float4*)(x + (((size_t)b * 256 + g * 32 + ic) * 32 + h) * 32 + w);
        xTl[(w + 0) * 40 + ic] = (f16)xv.x;
        xTl[(w + 1) * 40 + ic] = (f16)xv.y;
        xTl[(w + 2) * 40 + ic] = (f16)xv.z;
        xTl[(w + 3) * 40 + ic] = (f16)xv.w;
    }
    __syncthreads();

    int l15 = t & 15, quad = (t >> 4) & 3, wave = t >> 6;

    f16x8 xf0 = *(const f16x8*)(xTl + l15 * 40 + quad * 8);
    f16x8 xf1 = *(const f16x8*)(xTl + (16 + l15) * 40 + quad * 8);

    // ---- Q: A=wq rows=oc; wave covers oc-tiles wave*2 + {0,1} ----
#pragma unroll
    for (int i = 0; i < 2; ++i) {
        int mq = wave * 2 + i;  // oc-tile 0..7
        f16x8 wf = cvt8(wq + ((size_t)g * 128 + mq * 16 + l15) * 32 + quad * 8);
        float4 b4 = *(const float4*)(bq + g * 128 + mq * 16 + quad * 4);
#pragma unroll
        for (int Nt = 0; Nt < 2; ++Nt) {
            f32x4 d = {0.f, 0.f, 0.f, 0.f};
            d = MFMA_F16(wf, Nt ? xf1 : xf0, d);
            f16x4 q4;
            q4[0] = (f16)(d[0] + b4.x); q4[1] = (f16)(d[1] + b4.y);
            q4[2] = (f16)(d[2] + b4.z); q4[3] = (f16)(d[3] + b4.w);
            int w = Nt * 16 + l15;
            *(f16x4*)(Qb + (size_t)((b * 32 + h) * 32 + w) * 1024 + g * 128 + mq * 16 + quad * 4) = q4;
        }
    }

    if (wave < 2) {
        // ---- K: A=wk rows=c; wave = c-tile ----
        f16x8 wf = cvt8(wk + ((size_t)g * 32 + wave * 16 + l15) * 32 + quad * 8);
        float4 b4 = *(const float4*)(bk + g * 32 + wave * 16 + quad * 4);
#pragma unroll
        for (int Nt = 0; Nt < 2; ++Nt) {
            f32x4 d = {0.f, 0.f, 0.f, 0.f};
            d = MFMA_F16(wf, Nt ? xf1 : xf0, d);
            f16x4 k4;
            k4[0] = (f16)(d[0] + b4.x); k4[1] = (f16)(d[1] + b4.y);
            k4[2] = (f16)(d[2] + b4.z); k4[3] = (f16)(d[3] + b4.w);
            int wp = Nt * 16 + l15 + 3;
            *(f16x4*)(Kb + ((kvbase * 38 + hp) * 38 + wp) * 32 + wave * 16 + quad * 4) = k4;
        }
    } else {
        // ---- V: A=x^T rows=wp; wave-2 = c-tile ----
        int Nt = wave - 2;
        f16x8 wf = cvt8(wv + ((size_t)g * 32 + Nt * 16 + l15) * 32 + quad * 8);
        float bias = bv[g * 32 + Nt * 16 + l15];
        int c = Nt * 16 + l15;
        size_t vo = ((kvbase * 32 + c) * 38 + hp) * 40;
#pragma unroll
        for (int Mt = 0; Mt < 2; ++Mt) {
            f32x4 d = {0.f, 0.f, 0.f, 0.f};
            d = MFMA_F16(Mt ? xf1 : xf0, wf, d);
            __bf16 v0 = (__bf16)(d[0] + bias), v1 = (__bf16)(d[1] + bias);
            __bf16 v2 = (__bf16)(d[2] + bias), v3 = (__bf16)(d[3] + bias);
            int wp0 = Mt * 16 + quad * 4 + 3;  // odd start
            VtA[vo + wp0] = v0;
            bf16x2 mid; mid[0] = v1; mid[1] = v2;
            *(bf16x2*)(VtA + vo + wp0 + 1) = mid;   // idx even -> 4B aligned
            VtA[vo + wp0 + 3] = v3;
            bf16x4a4 p4; p4[0] = v0; p4[1] = v1; p4[2] = v2; p4[3] = v3;
            *(bf16x4a4*)(VtB + vo + wp0 - 1) = p4;  // idx even -> 4B aligned
        }
    }

    // ---- wp borders (bias) + zero pads ----
    for (int idx = t; idx < 192; idx += 256) {
        int wi = idx >> 5, c = idx & 31;
        int wp = (wi < 3) ? wi : (32 + wi);  // {0,1,2,35,36,37}
        Kb[((kvbase * 38 + hp) * 38 + wp) * 32 + c] = (f16)bk[g * 32 + c];
        size_t vo = ((kvbase * 32 + c) * 38 + hp) * 40;
        __bf16 bb = (__bf16)bv[g * 32 + c];
        VtA[vo + wp] = bb;
        if (wp >= 1) VtB[vo + wp - 1] = bb;
    }
    for (int idx = t; idx < 160; idx += 256) {  // VtA idx 38,39; VtB idx 37,38,39
        int c = idx / 5, j = idx % 5;
        size_t vo = ((kvbase * 32 + c) * 38 + hp) * 40;
        if (j < 2) VtA[vo + 38 + j] = (__bf16)0.f;
        else       VtB[vo + 35 + j] = (__bf16)0.f;
    }
}

// ---------------------------------------------------------------------------
// MFMA attention, split-K: 2 waves per position (wave w handles gp 4w..4w+3),
// zero-LDS main loop (P register-resident via transposed scores), cross-wave
// combine of partial O^T + fsum through 5 KB LDS, one barrier.
// __launch_bounds__(128, 4): R8's body compiled to 64 VGPR / no spill under
// this bound; (128,8) forced 32 arch-VGPRs and spilled 380 MB/iter (R9).
// ---------------------------------------------------------------------------
__global__ __launch_bounds__(128, 4) void attn_kernel(
    const f16* __restrict__ Qb, const f16* __restrict__ Kb,
    const __bf16* __restrict__ VtA, const __bf16* __restrict__ VtB,
    const f16* __restrict__ relp, float* __restrict__ out) {
    int bid = blockIdx.x;
    int t = threadIdx.x;
    int wvi = t >> 6;
    int pid = (bid & 7) * 512 + (bid >> 3);  // XCD swizzle, one position/block
    int y = pid & 31, x = (pid >> 5) & 31, b = pid >> 10;

    __shared__ __align__(16) float accS[64 * 20];  // wave1 partials, stride 20

    int lane = t & 63;
    int l15 = lane & 15, quad = lane >> 4, kwl = lane & 7, p8 = (lane >> 3) & 1;
    bool oddq = (quad & 1);
    int kw0 = (quad & 1) * 4;
    int gph = quad >> 1;

    // Q fragments (B-role: n=qi=l15, k=c=quad*8+j)
    f16x8 qf[2];
    {
        const f16* qp = Qb + (size_t)pid * 1024;
        qf[0] = *(const f16x8*)(qp + l15 * 32 + quad * 8);
        qf[1] = *(const f16x8*)(qp + (16 + l15) * 32 + quad * 8);
    }

    float fsumT[2] = {0.f, 0.f};
    f32x4 acc[2][2];  // [ct][Mt]: O^T rows c=ct*16+quad*4+r, cols qi tile Mt
#pragma unroll
    for (int ct = 0; ct < 2; ++ct)
#pragma unroll
        for (int m = 0; m < 2; ++m) acc[ct][m] = (f32x4){0.f, 0.f, 0.f, 0.f};

    int yk = y + kwl;
    if (yk > 37) yk = 37;  // masked row: clamp (finite garbage, exp->0)
    const __bf16* __restrict__ Vsel = (y & 1) ? VtB : VtA;
    int yv = (y & ~1) + kw0;

    for (int chunk = wvi * 2; chunk < wvi * 2 + 2; ++chunk) {
        int gpr = chunk * 2 + p8;   // this lane's key-row group (K/relp)
        int gpv = chunk * 2 + gph;  // this lane's V-fragment group
        const f16* kbp = Kb + ((((size_t)(b * 8 + gpr) * 38 + x) * 38 + yk) << 5) + quad * 8;
        const f16* rpp = relp + ((size_t)(gpr * 56 + kwl) << 5) + quad * 8;
        const __bf16* vp0 = Vsel + (((size_t)(b * 8 + gpv) * 32 + l15) * 38 + x) * 40 + yv;
        const __bf16* vp1 = vp0 + (size_t)16 * 38 * 40;
#pragma unroll
        for (int kh = 0; kh < 7; ++kh) {
            f16x8 kb = *(const f16x8*)kbp;  kbp += 38 * 32;
            f16x8 rp = *(const f16x8*)rpp;  rpp += 256;
            kb += rp;  // K' = K + rel'
            s16x4a4 vf0 = *(const s16x4a4*)vp0;  vp0 += 40;
            s16x4a4 vf1 = *(const s16x4a4*)vp1;  vp1 += 40;
#pragma unroll
            for (int Mt = 0; Mt < 2; ++Mt) {
                f32x4 d = {0.f, 0.f, 0.f, 0.f};
                d = MFMA_F16(kb, qf[Mt], d);  // S^T: rows=keys, cols=qi
                float e0 = __expf(d[0]);
                float e1 = __expf(d[1]);
                float e2 = __expf(d[2]);
                float e3 = oddq ? 0.f : __expf(d[3]);  // kw=7 mask
                fsumT[Mt] += (e0 + e1) + (e2 + e3);
                bf16x4 pb;
                pb[0] = (__bf16)e0; pb[1] = (__bf16)e1;
                pb[2] = (__bf16)e2; pb[3] = (__bf16)e3;
                s16x4 pbi = __builtin_bit_cast(s16x4, pb);
                acc[0][Mt] = MFMA_BF16_K16((s16x4)vf0, pbi, acc[0][Mt]);
                acc[1][Mt] = MFMA_BF16_K16((s16x4)vf1, pbi, acc[1][Mt]);
            }
        }
    }

    // ---- intra-wave fsum reduce across quads ----
#pragma unroll
    for (int m = 0; m < 2; ++m) {
        fsumT[m] += __shfl_xor(fsumT[m], 16);
        fsumT[m] += __shfl_xor(fsumT[m], 32);
    }

    // ---- cross-wave combine ----
    if (wvi == 1) {
        float* s = accS + lane * 20;
        *(f32x4*)(s + 0)  = acc[0][0];
        *(f32x4*)(s + 4)  = acc[0][1];
        *(f32x4*)(s + 8)  = acc[1][0];
        *(f32x4*)(s + 12) = acc[1][1];
        s[16] = fsumT[0];
        s[17] = fsumT[1];
    }
    __syncthreads();
    if (wvi == 1) return;

    {
        const float* s = accS + lane * 20;
        acc[0][0] += *(const f32x4*)(s + 0);
        acc[0][1] += *(const f32x4*)(s + 4);
        acc[1][0] += *(const f32x4*)(s + 8);
        acc[1][1] += *(const f32x4*)(s + 12);
        fsumT[0] += s[16];
        fsumT[1] += s[17];
    }
    float inv[2] = {1.0f / fsumT[0], 1.0f / fsumT[1]};

    // ---- epilogue: normalize (lane-uniform inv), head-sum over l15&3 ----
#pragma unroll
    for (int Mt = 0; Mt < 2; ++Mt)
#pragma unroll
        for (int ct = 0; ct < 2; ++ct) {
            float v[4];
#pragma unroll
            for (int r = 0; r < 4; ++r) {
                v[r] = acc[ct][Mt][r] * inv[Mt];
                v[r] += __shfl_xor(v[r], 1);
                v[r] += __shfl_xor(v[r], 2);
            }
            if ((l15 & 3) == 0) {
                int g = Mt * 4 + (l15 >> 2);
                float4 o4 = {v[0], v[1], v[2], v[3]};
                *(float4*)(out + ((((size_t)(b * 8 + g) * 32 + x) * 32 + y) << 5) +
                           ct * 16 + quad * 4) = o4;
            }
        }
}

// ---------------------------------------------------------------------------
extern "C" void kernel_launch(void* const* d_in, const int* in_sizes, int n_in,
                              void* d_out, int out_size, void* d_ws, size_t ws_size,
                              hipStream_t stream) {
    const float* x     = (const float*)d_in[0];
    const float* wq    = (const float*)d_in[1];
    const float* bq    = (const float*)d_in[2];
    const float* wk    = (const float*)d_in[3];
    const float* bk    = (const float*)d_in[4];
    const float* wv    = (const float*)d_in[5];
    const float* bv    = (const float*)d_in[6];
    const float* rel_h = (const float*)d_in[7];
    const float* rel_w = (const float*)d_in[8];
    float* out = (float*)d_out;

    // ws layout (bytes):
    //   Qb  f16 : 4096*1024*2        = 8,388,608
    //   Kb  f16 : 4*8*38*38*32*2     = 2,957,312
    //   VtA bf16: 4*8*32*38*40*2     = 3,112,960
    //   VtB bf16: 3,112,960
    //   relp f16: 448*32*2           = 28,672
    unsigned char* ws = (unsigned char*)d_ws;
    f16*    Qb   = (f16*)ws;
    f16*    Kb   = (f16*)(ws + 8388608);
    __bf16* VtA  = (__bf16*)(ws + 8388608 + 2957312);
    __bf16* VtB  = (__bf16*)(ws + 8388608 + 2957312 + 3112960);
    f16*    relp = (f16*)(ws + 8388608 + 2957312 + 3112960 + 3112960);

    hipLaunchKernelGGL(produce_kernel, dim3(1217), dim3(256), 0, stream,
                       x, wq, bq, wk, bk, wv, bv, rel_h, rel_w, Qb, Kb, VtA, VtB, relp);
    hipLaunchKernelGGL(attn_kernel, dim3(4096), dim3(128), 0, stream,
                       Qb, Kb, VtA, VtB, relp, out);
}

// Round 11
// 120.070 us; speedup vs baseline: 1.7905x; 1.0770x over previous
//
#include <hip/hip_runtime.h>
#include <math.h>

typedef _Float16 f16;
typedef _Float16 f16x4 __attribute__((ext_vector_type(4)));
typedef _Float16 f16x8 __attribute__((ext_vector_type(8)));
typedef __bf16 bf16x2 __attribute__((ext_vector_type(2)));
typedef __bf16 bf16x4 __attribute__((ext_vector_type(4)));
typedef __bf16 bf16x4a8 __attribute__((ext_vector_type(4), aligned(8)));
typedef short s16x4 __attribute__((ext_vector_type(4)));
typedef float f32x4 __attribute__((ext_vector_type(4)));

#define MFMA_F16(a, b, c)  __builtin_amdgcn_mfma_f32_16x16x32_f16(a, b, c, 0, 0, 0)
#define MFMA_BF16_K16(a, b, c) __builtin_amdgcn_mfma_f32_16x16x16bf16_1k(a, b, c, 0, 0, 0)

#define VSS 12160  // panels per shift = 32 bg * 38 hp * 10

static __device__ inline f16x8 cvt8(const float* p) {
    const float4* p4 = (const float4*)p;
    float4 u0 = p4[0], u1 = p4[1];
    f16x8 r;
    r[0] = (f16)u0.x; r[1] = (f16)u0.y; r[2] = (f16)u0.z; r[3] = (f16)u0.w;
    r[4] = (f16)u1.x; r[5] = (f16)u1.y; r[6] = (f16)u1.z; r[7] = (f16)u1.w;
    return r;
}

// ---------------------------------------------------------------------------
// Fused producer. Blocks 0..1215: (b,g,hp) rows -> Q,K,V via f16 MFMA;
// block 1216 builds relp.
// Layouts: Qb f16 [pos][g*128+oc]; Kb f16 [b][g][hp][wp][c];
//   V4 bf16, 4 wp-shifted panel copies: V4[s][bg][hp][panel p][c][wp4]
//   (panel = 128 bf16 = 32 c x 4 wp; slot (s,p,o) holds wp = s + 4p + o).
// ---------------------------------------------------------------------------
__global__ __launch_bounds__(256) void produce_kernel(
    const float* __restrict__ x,
    const float* __restrict__ wq, const float* __restrict__ bq,
    const float* __restrict__ wk, const float* __restrict__ bk,
    const float* __restrict__ wv, const float* __restrict__ bv,
    const float* __restrict__ rel_h, const float* __restrict__ rel_w,
    f16* __restrict__ Qb, f16* __restrict__ Kb,
    __bf16* __restrict__ V4, f16* __restrict__ relp) {
    int bid = blockIdx.x;
    int t = threadIdx.x;

    if (bid == 1216) {  // rel' table: key=(gp*7+kh)*8+kw, channel c
        for (int idx = t; idx < 448 * 32; idx += 256) {
            int c = idx & 31, key = idx >> 5;
            int kw = key & 7, ghk = key >> 3;
            int gp = (ghk * 37) >> 8;
            int kh = ghk - gp * 7;
            float v = 0.f;
            if (kw < 7)
                v = (c < 16) ? rel_h[c * 56 + gp * 7 + kh]
                             : rel_w[(c - 16) * 56 + gp * 7 + kw];
            relp[idx] = (f16)v;
        }
        return;
    }

    int hp = bid % 38, g = (bid / 38) & 7, b = bid / 304;
    bool hin = (hp >= 3 && hp < 35);
    size_t kvbase = (size_t)(b * 8 + g);
    size_t rowp = (kvbase * 38 + hp) * 10;  // panel row (within one shift)

    if (!hin) {  // pure-bias row (h padding)
        for (int idx = t; idx < 38 * 32; idx += 256) {
            int wp = idx >> 5, c = idx & 31;
            Kb[((kvbase * 38 + hp) * 38 + wp) * 32 + c] = (f16)bk[g * 32 + c];
        }
        for (int idx = t; idx < 4 * 40 * 32; idx += 256) {  // s, w', c
            int c = idx & 31, w = (idx >> 5) % 40, s = (idx >> 5) / 40;
            int wp = s + w;  // slot (s, w>>2, w&3)
            __bf16 val = (wp <= 37) ? (__bf16)bv[g * 32 + c] : (__bf16)0.f;
            V4[((size_t)s * VSS + rowp + (w >> 2)) * 128 + c * 4 + (w & 3)] = val;
        }
        return;
    }

    int h = hp - 3;
    __shared__ __align__(16) f16 xTl[32 * 40];  // [w][ic], stride 40

    {   // stage x^T (each thread one float4 along w)
        int ic = t >> 3, w = (t & 7) * 4;
        float4 xv = *(const float4*)(x + (((size_t)b * 256 + g * 32 + ic) * 32 + h) * 32 + w);
        xTl[(w + 0) * 40 + ic] = (f16)xv.x;
        xTl[(w + 1) * 40 + ic] = (f16)xv.y;
        xTl[(w + 2) * 40 + ic] = (f16)xv.z;
        xTl[(w + 3) * 40 + ic] = (f16)xv.w;
    }
    __syncthreads();

    int l15 = t & 15, quad = (t >> 4) & 3, wave = t >> 6;

    f16x8 xf0 = *(const f16x8*)(xTl + l15 * 40 + quad * 8);
    f16x8 xf1 = *(const f16x8*)(xTl + (16 + l15) * 40 + quad * 8);

    // ---- Q: A=wq rows=oc; wave covers oc-tiles wave*2 + {0,1} ----
#pragma unroll
    for (int i = 0; i < 2; ++i) {
        int mq = wave * 2 + i;  // oc-tile 0..7
        f16x8 wf = cvt8(wq + ((size_t)g * 128 + mq * 16 + l15) * 32 + quad * 8);
        float4 b4 = *(const float4*)(bq + g * 128 + mq * 16 + quad * 4);
#pragma unroll
        for (int Nt = 0; Nt < 2; ++Nt) {
            f32x4 d = {0.f, 0.f, 0.f, 0.f};
            d = MFMA_F16(wf, Nt ? xf1 : xf0, d);
            f16x4 q4;
            q4[0] = (f16)(d[0] + b4.x); q4[1] = (f16)(d[1] + b4.y);
            q4[2] = (f16)(d[2] + b4.z); q4[3] = (f16)(d[3] + b4.w);
            int w = Nt * 16 + l15;
            *(f16x4*)(Qb + (size_t)((b * 32 + h) * 32 + w) * 1024 + g * 128 + mq * 16 + quad * 4) = q4;
        }
    }

    if (wave < 2) {
        // ---- K: A=wk rows=c; wave = c-tile ----
        f16x8 wf = cvt8(wk + ((size_t)g * 32 + wave * 16 + l15) * 32 + quad * 8);
        float4 b4 = *(const float4*)(bk + g * 32 + wave * 16 + quad * 4);
#pragma unroll
        for (int Nt = 0; Nt < 2; ++Nt) {
            f32x4 d = {0.f, 0.f, 0.f, 0.f};
            d = MFMA_F16(wf, Nt ? xf1 : xf0, d);
            f16x4 k4;
            k4[0] = (f16)(d[0] + b4.x); k4[1] = (f16)(d[1] + b4.y);
            k4[2] = (f16)(d[2] + b4.z); k4[3] = (f16)(d[3] + b4.w);
            int wp = Nt * 16 + l15 + 3;
            *(f16x4*)(Kb + ((kvbase * 38 + hp) * 38 + wp) * 32 + wave * 16 + quad * 4) = k4;
        }
    } else {
        // ---- V: A=x^T rows=wp; wave-2 = c-tile; write 4 shifted panel copies
        int Nt = wave - 2;
        f16x8 wf = cvt8(wv + ((size_t)g * 32 + Nt * 16 + l15) * 32 + quad * 8);
        float bias = bv[g * 32 + Nt * 16 + l15];
        int c = Nt * 16 + l15;
#pragma unroll
        for (int Mt = 0; Mt < 2; ++Mt) {
            f32x4 d = {0.f, 0.f, 0.f, 0.f};
            d = MFMA_F16(Mt ? xf1 : xf0, wf, d);
            __bf16 v0 = (__bf16)(d[0] + bias), v1 = (__bf16)(d[1] + bias);
            __bf16 v2 = (__bf16)(d[2] + bias), v3 = (__bf16)(d[3] + bias);
            // wp0 = Mt*16+quad*4+3 -> wp0 mod 4 == 3, p0 = Mt*4+quad for all s
            int p0 = Mt * 4 + quad;
            __bf16* P0 = V4 + ((size_t)0 * VSS + rowp + p0) * 128 + c * 4;  // s=0
            __bf16* P1 = V4 + ((size_t)1 * VSS + rowp + p0) * 128 + c * 4;  // s=1
            __bf16* P2 = V4 + ((size_t)2 * VSS + rowp + p0) * 128 + c * 4;  // s=2
            __bf16* P3 = V4 + ((size_t)3 * VSS + rowp + p0) * 128 + c * 4;  // s=3
            // s=3: r=0 -> one aligned 8B store
            { bf16x4a8 q; q[0] = v0; q[1] = v1; q[2] = v2; q[3] = v3; *(bf16x4a8*)P3 = q; }
            // s=2: r=1 -> o1:v0, o2-3:(v1,v2), next panel o0:v3
            { P2[1] = v0; bf16x2 m; m[0] = v1; m[1] = v2; *(bf16x2*)(P2 + 2) = m; P2[128] = v3; }
            // s=1: r=2 -> o2-3:(v0,v1), next panel o0-1:(v2,v3)
            { bf16x2 m; m[0] = v0; m[1] = v1; *(bf16x2*)(P1 + 2) = m;
              bf16x2 n; n[0] = v2; n[1] = v3; *(bf16x2*)(P1 + 128) = n; }
            // s=0: r=3 -> o3:v0, next panel o0-1:(v1,v2), o2:v3
            { P0[3] = v0; bf16x2 m; m[0] = v1; m[1] = v2; *(bf16x2*)(P0 + 128) = m; P0[130] = v3; }
        }
    }

    // ---- wp borders (bias) + zero tails ----
    for (int idx = t; idx < 192; idx += 256) {  // Kb borders
        int wi = idx >> 5, c = idx & 31;
        int wp = (wi < 3) ? wi : (32 + wi);  // {0,1,2,35,36,37}
        Kb[((kvbase * 38 + hp) * 38 + wp) * 32 + c] = (f16)bk[g * 32 + c];
    }
    for (int idx = t; idx < 4 * 6 * 32; idx += 256) {  // V4 borders, per shift
        int c = idx & 31, wi = (idx >> 5) % 6, s = (idx >> 5) / 6;
        int wp = (wi < 3) ? wi : (32 + wi);
        if (wp >= s) {
            int w = wp - s;
            V4[((size_t)s * VSS + rowp + (w >> 2)) * 128 + c * 4 + (w & 3)] =
                (__bf16)bv[g * 32 + c];
        }
    }
    for (int idx = t; idx < 4 * 5 * 32; idx += 256) {  // V4 zero tails wp>=38
        int c = idx & 31, j = (idx >> 5) % 5, s = (idx >> 5) / 5;
        int w = 35 + j;  // slot w' -> wp = s + w
        if (s + w >= 38)
            V4[((size_t)s * VSS + rowp + (w >> 2)) * 128 + c * 4 + (w & 3)] = (__bf16)0.f;
    }
}

// ---------------------------------------------------------------------------
// MFMA attention, split-K (R10 structure): 2 waves/position, zero-LDS main
// loop, register-resident P (transposed scores), cross-wave combine via LDS.
// V loads now hit the V4 panel layout: 8-B load, lanes (c) contiguous ->
// 8 fully-utilized lines/instr (was 32 @ 12.5%).
// __launch_bounds__(128,4): (128,8) forced 32 VGPR + spills (R9).
// ---------------------------------------------------------------------------
__global__ __launch_bounds__(128, 4) void attn_kernel(
    const f16* __restrict__ Qb, const f16* __restrict__ Kb,
    const __bf16* __restrict__ V4, const f16* __restrict__ relp,
    float* __restrict__ out) {
    int bid = blockIdx.x;
    int t = threadIdx.x;
    int wvi = t >> 6;
    int pid = (bid & 7) * 512 + (bid >> 3);  // XCD swizzle, one position/block
    int y = pid & 31, x = (pid >> 5) & 31, b = pid >> 10;

    __shared__ __align__(16) float accS[64 * 20];  // wave1 partials, stride 20

    int lane = t & 63;
    int l15 = lane & 15, quad = lane >> 4, kwl = lane & 7, p8 = (lane >> 3) & 1;
    bool oddq = (quad & 1);

    // Q fragments (B-role: n=qi=l15, k=c=quad*8+j)
    f16x8 qf[2];
    {
        const f16* qp = Qb + (size_t)pid * 1024;
        qf[0] = *(const f16x8*)(qp + l15 * 32 + quad * 8);
        qf[1] = *(const f16x8*)(qp + (16 + l15) * 32 + quad * 8);
    }

    float fsumT[2] = {0.f, 0.f};
    f32x4 acc[2][2];  // [ct][Mt]: O^T rows c=ct*16+quad*4+r, cols qi tile Mt
#pragma unroll
    for (int ct = 0; ct < 2; ++ct)
#pragma unroll
        for (int m = 0; m < 2; ++m) acc[ct][m] = (f32x4){0.f, 0.f, 0.f, 0.f};

    int yk = y + kwl;
    if (yk > 37) yk = 37;  // masked row: clamp (finite garbage, exp->0)
    int s = y & 3;
    // V panel index parts: panel = (y>>2) + (quad&1); lane offset c*4 (c=l15 / +16)
    size_t vshift = (size_t)s * VSS;

    for (int chunk = wvi * 2; chunk < wvi * 2 + 2; ++chunk) {
        int gpr = chunk * 2 + p8;           // this lane's key-row group (K/relp)
        int gpv = chunk * 2 + (quad >> 1);  // this lane's V-fragment group
        const f16* kbp = Kb + ((((size_t)(b * 8 + gpr) * 38 + x) * 38 + yk) << 5) + quad * 8;
        const f16* rpp = relp + ((size_t)(gpr * 56 + kwl) << 5) + quad * 8;
        const __bf16* vp0 = V4 +
            ((vshift + ((size_t)(b * 8 + gpv) * 38 + x) * 10 + (y >> 2) + (quad & 1)) << 7) +
            l15 * 4;
        const __bf16* vp1 = vp0 + 64;  // c + 16
#pragma unroll
        for (int kh = 0; kh < 7; ++kh) {
            f16x8 kb = *(const f16x8*)kbp;  kbp += 38 * 32;
            f16x8 rp = *(const f16x8*)rpp;  rpp += 256;
            kb += rp;  // K' = K + rel'
            s16x4 vf0 = *(const s16x4*)vp0;  vp0 += 1280;
            s16x4 vf1 = *(const s16x4*)vp1;  vp1 += 1280;
#pragma unroll
            for (int Mt = 0; Mt < 2; ++Mt) {
                f32x4 d = {0.f, 0.f, 0.f, 0.f};
                d = MFMA_F16(kb, qf[Mt], d);  // S^T: rows=keys, cols=qi
                float e0 = __expf(d[0]);
                float e1 = __expf(d[1]);
                float e2 = __expf(d[2]);
                float e3 = oddq ? 0.f : __expf(d[3]);  // kw=7 mask
                fsumT[Mt] += (e0 + e1) + (e2 + e3);
                bf16x4 pb;
                pb[0] = (__bf16)e0; pb[1] = (__bf16)e1;
                pb[2] = (__bf16)e2; pb[3] = (__bf16)e3;
                s16x4 pbi = __builtin_bit_cast(s16x4, pb);
                acc[0][Mt] = MFMA_BF16_K16(vf0, pbi, acc[0][Mt]);
                acc[1][Mt] = MFMA_BF16_K16(vf1, pbi, acc[1][Mt]);
            }
        }
    }

    // ---- intra-wave fsum reduce across quads ----
#pragma unroll
    for (int m = 0; m < 2; ++m) {
        fsumT[m] += __shfl_xor(fsumT[m], 16);
        fsumT[m] += __shfl_xor(fsumT[m], 32);
    }

    // ---- cross-wave combine ----
    if (wvi == 1) {
        float* sp = accS + lane * 20;
        *(f32x4*)(sp + 0)  = acc[0][0];
        *(f32x4*)(sp + 4)  = acc[0][1];
        *(f32x4*)(sp + 8)  = acc[1][0];
        *(f32x4*)(sp + 12) = acc[1][1];
        sp[16] = fsumT[0];
        sp[17] = fsumT[1];
    }
    __syncthreads();
    if (wvi == 1) return;

    {
        const float* sp = accS + lane * 20;
        acc[0][0] += *(const f32x4*)(sp + 0);
        acc[0][1] += *(const f32x4*)(sp + 4);
        acc[1][0] += *(const f32x4*)(sp + 8);
        acc[1][1] += *(const f32x4*)(sp + 12);
        fsumT[0] += sp[16];
        fsumT[1] += sp[17];
    }
    float inv[2] = {1.0f / fsumT[0], 1.0f / fsumT[1]};

    // ---- epilogue: normalize (lane-uniform inv), head-sum over l15&3 ----
#pragma unroll
    for (int Mt = 0; Mt < 2; ++Mt)
#pragma unroll
        for (int ct = 0; ct < 2; ++ct) {
            float v[4];
#pragma unroll
            for (int r = 0; r < 4; ++r) {
                v[r] = acc[ct][Mt][r] * inv[Mt];
                v[r] += __shfl_xor(v[r], 1);
                v[r] += __shfl_xor(v[r], 2);
            }
            if ((l15 & 3) == 0) {
                int g = Mt * 4 + (l15 >> 2);
                float4 o4 = {v[0], v[1], v[2], v[3]};
                *(float4*)(out + ((((size_t)(b * 8 + g) * 32 + x) * 32 + y) << 5) +
                           ct * 16 + quad * 4) = o4;
            }
        }
}

// ---------------------------------------------------------------------------
extern "C" void kernel_launch(void* const* d_in, const int* in_sizes, int n_in,
                              void* d_out, int out_size, void* d_ws, size_t ws_size,
                              hipStream_t stream) {
    const float* x     = (const float*)d_in[0];
    const float* wq    = (const float*)d_in[1];
    const float* bq    = (const float*)d_in[2];
    const float* wk    = (const float*)d_in[3];
    const float* bk    = (const float*)d_in[4];
    const float* wv    = (const float*)d_in[5];
    const float* bv    = (const float*)d_in[6];
    const float* rel_h = (const float*)d_in[7];
    const float* rel_w = (const float*)d_in[8];
    float* out = (float*)d_out;

    // ws layout (bytes):
    //   Qb  f16 : 4096*1024*2            = 8,388,608
    //   Kb  f16 : 4*8*38*38*32*2         = 2,957,312
    //   V4  bf16: 4 shifts * 12160*128*2 = 12,451,840
    //   relp f16: 448*32*2               = 28,672
    unsigned char* ws = (unsigned char*)d_ws;
    f16*    Qb   = (f16*)ws;
    f16*    Kb   = (f16*)(ws + 8388608);
    __bf16* V4   = (__bf16*)(ws + 8388608 + 2957312);
    f16*    relp = (f16*)(ws + 8388608 + 2957312 + 12451840);

    hipLaunchKernelGGL(produce_kernel, dim3(1217), dim3(256), 0, stream,
                       x, wq, bq, wk, bk, wv, bv, rel_h, rel_w, Qb, Kb, V4, relp);
    hipLaunchKernelGGL(attn_kernel, dim3(4096), dim3(128), 0, stream,
                       Qb, Kb, V4, relp, out);
}